// Round 5
// baseline (85.409 us; speedup 1.0000x reference)
//
#include <hip/hip_runtime.h>
#include <hip/hip_bf16.h>
#include <math.h>

// Problem constants (B=4096, D=128, T=0.5 -> 1/T = 2)
#define BB       4096
#define N2       8192          // 2B rows of z
#define DIMS     128
#define NT       32            // number of 256-row tiles per matrix side
#define NJOBS    (NT * (NT + 1) / 2)   // 528 upper-triangle tile jobs
#define TILE     256           // rows/cols per tile job
#define ROWTILES 4             // 16-row MFMA rowtiles per wave (wave owns 64 rows)
#define LDS_PAD  8             // bf16 pad per row: breaks 256B-stride 16B-group conflicts
#define LDS_ROWW (DIMS + LDS_PAD)  // 136 shorts = 272 B

// z rows are pre-scaled by ZSCALE so the MFMA dot directly yields
// sim * 2*log2(e), i.e. exp(sim/T) = exp2(acc). ZSCALE^2 = 2.8853900818.
#define ZSCALE   1.6986436f
// diagonal term exp(2 * |z_r|^2) ~= exp(2) — subtracted in reduce.
#define DIAG_E2  7.38905609893065f

typedef __attribute__((ext_vector_type(8))) short short8;   // 8 x bf16 (4 VGPRs)
typedef __attribute__((ext_vector_type(4))) float float4v;  // MFMA C/D

// ---------------------------------------------------------------------------
// Kernel 1: normalize rows (fp32), compute positives (fp32), write z as
// bf16 scaled by ZSCALE. One wave per row-pair r: emb_i[r] -> z[r],
// emb_j[r] -> z[r+B]. P needs no zero-init (every cell written once).
// ---------------------------------------------------------------------------
__global__ __launch_bounds__(256) void norm_kernel(
    const float* __restrict__ emb_i, const float* __restrict__ emb_j,
    __hip_bfloat16* __restrict__ z, float* __restrict__ pos) {
  int gw   = (blockIdx.x * blockDim.x + threadIdx.x) >> 6;  // row pair
  int lane = threadIdx.x & 63;
  if (gw >= BB) return;

  const float2* ei = (const float2*)(emb_i + (size_t)gw * DIMS);
  const float2* ej = (const float2*)(emb_j + (size_t)gw * DIMS);
  float2 a = ei[lane];
  float2 b = ej[lane];

  float sa = a.x * a.x + a.y * a.y;
  float sb = b.x * b.x + b.y * b.y;
  #pragma unroll
  for (int m = 32; m; m >>= 1) {
    sa += __shfl_xor(sa, m, 64);
    sb += __shfl_xor(sb, m, 64);
  }
  float inva = 1.0f / fmaxf(sqrtf(sa), 1e-12f);
  float invb = 1.0f / fmaxf(sqrtf(sb), 1e-12f);

  float zi0 = a.x * inva, zi1 = a.y * inva;
  float zj0 = b.x * invb, zj1 = b.y * invb;

  // positive pair dot in unscaled fp32 (matches reference's fp32 einsum)
  float p = zi0 * zj0 + zi1 * zj1;
  #pragma unroll
  for (int m = 32; m; m >>= 1) p += __shfl_xor(p, m, 64);
  if (lane == 0) pos[gw] = p;

  __hip_bfloat162* zr_i = (__hip_bfloat162*)(z + (size_t)gw * DIMS);
  __hip_bfloat162* zr_j = (__hip_bfloat162*)(z + (size_t)(gw + BB) * DIMS);
  __hip_bfloat162 vi, vj;
  vi.x = __float2bfloat16(zi0 * ZSCALE); vi.y = __float2bfloat16(zi1 * ZSCALE);
  vj.x = __float2bfloat16(zj0 * ZSCALE); vj.y = __float2bfloat16(zj1 * ZSCALE);
  zr_i[lane] = vi;
  zr_j[lane] = vj;
}

// ---------------------------------------------------------------------------
// Kernel 2: symmetric fused sim-GEMM + exp2 -> private partials (no atomics).
// Round-4 post-mortem: 2080 tiny blocks were per-block-latency-bound
// (~25 µs for ~3 µs of math; 8 sequential block-rounds/CU). This version
// quadruples the tile to 256x256 over a 32x32 grid -> 528 blocks = ONE
// scheduling round at 2 blocks/CU (LDS-bound: 73.7 KB), so setup latency
// is paid once and overlapped. Per wave: 4 rowtiles (64 rows) of A pinned
// in 64 VGPRs, 16 coltiles from LDS, 256 MFMAs + 1024 exp2.
// Block (I,J), I<J writes row-partials to P[I][J][:] and col-partials to
// P[J][I][:]; diag writes P[I][I][:] only. Every cell written exactly once.
// MFMA dot is bit-identical under operand transpose, so symmetry is exact.
// ---------------------------------------------------------------------------
__global__ __launch_bounds__(256, 2) void simloss_sym(
    const __hip_bfloat16* __restrict__ z, float* __restrict__ P) {
  __shared__ short lds[TILE * LDS_ROWW];   // 256 x 136 bf16 = 69632 B
  __shared__ float csum_lds[4][TILE];      // per-wave column-sum partials, 4 KB

  const int tid  = threadIdx.x;
  const int wave = tid >> 6;
  const int lane = tid & 63;
  const int lr   = lane & 15;          // A-row / B-col / C-col within 16-tile
  const int quad = lane >> 4;          // k-group for A/B, row-group for C

  // ---- decode flat job id -> (I, J) with I <= J over NT=32 ----
  // base(I) = I*(2*NT - I + 1)/2 = I*(65-I)/2 ; float guess + integer fixup.
  const int j = blockIdx.x;
  int I = (int)((65.0f - sqrtf(4225.0f - 8.0f * (float)j)) * 0.5f);
  I = I < 0 ? 0 : (I > NT - 1 ? NT - 1 : I);
  while (I < NT - 1 && (I + 1) * (2 * NT - I) / 2 <= j) ++I;
  while (I > 0 && I * (2 * NT - I + 1) / 2 > j) --I;
  const int J = I + (j - I * (2 * NT - I + 1) / 2);
  const bool diag = (I == J);
  const int R0 = I * TILE;
  const int C0 = J * TILE;

  const ushort* zp = (const ushort*)z;

  // ---- A fragments pinned in VGPRs: rows R0 + wave*64 + rt*16 + lr ----
  short8 afrag[ROWTILES][4];
  #pragma unroll
  for (int rt = 0; rt < ROWTILES; rt++) {
    const int arow = R0 + wave * 64 + rt * 16 + lr;
    const short8* ap = (const short8*)(zp + (size_t)arow * DIMS + quad * 8);
    afrag[rt][0] = ap[0];
    afrag[rt][1] = ap[4];   // +32 shorts
    afrag[rt][2] = ap[8];
    afrag[rt][3] = ap[12];
  }

  // ---- stage B tile: 256 cols x 128 dims (4096 short8, 16 per thread) ----
  {
    const short8* src = (const short8*)(zp + (size_t)C0 * DIMS);
    #pragma unroll
    for (int i = 0; i < 16; i++) {
      int idx  = tid + 256 * i;        // linear short8 index
      int row  = idx >> 4;             // 16 short8 per logical row
      int col8 = idx & 15;
      *(short8*)&lds[row * LDS_ROWW + col8 * 8] = src[idx];
    }
  }
  __syncthreads();

  float rowsum[ROWTILES][4];
  #pragma unroll
  for (int rt = 0; rt < ROWTILES; rt++)
    #pragma unroll
    for (int r = 0; r < 4; r++) rowsum[rt][r] = 0.0f;

  #pragma unroll 4
  for (int t = 0; t < 16; t++) {       // 16 column tiles of 16
    const short8* bp = (const short8*)&lds[(t * 16 + lr) * LDS_ROWW + quad * 8];
    short8 b0 = bp[0];
    short8 b1 = bp[4];
    short8 b2 = bp[8];
    short8 b3 = bp[12];
    float ctile = 0.0f;
    #pragma unroll
    for (int rt = 0; rt < ROWTILES; rt++) {
      float4v acc = {0.0f, 0.0f, 0.0f, 0.0f};
      acc = __builtin_amdgcn_mfma_f32_16x16x32_bf16(afrag[rt][0], b0, acc, 0, 0, 0);
      acc = __builtin_amdgcn_mfma_f32_16x16x32_bf16(afrag[rt][1], b1, acc, 0, 0, 0);
      acc = __builtin_amdgcn_mfma_f32_16x16x32_bf16(afrag[rt][2], b2, acc, 0, 0, 0);
      acc = __builtin_amdgcn_mfma_f32_16x16x32_bf16(afrag[rt][3], b3, acc, 0, 0, 0);
      // exp(sim/T) = exp2(acc) thanks to ZSCALE pre-scaling.
      #pragma unroll
      for (int r = 0; r < 4; r++) {
        float e = __builtin_amdgcn_exp2f(acc[r]);
        rowsum[rt][r] += e;
        ctile += e;
      }
    }
    if (!diag) {  // block-uniform branch
      // column sums: reduce the wave's 64 rows (regs done above, now quads)
      ctile += __shfl_xor(ctile, 16, 64);
      ctile += __shfl_xor(ctile, 32, 64);
      if (quad == 0) csum_lds[wave][t * 16 + lr] = ctile;
    }
  }

  // ---- row sums: reduce across the 16 lanes of each quad, store float4 ----
  #pragma unroll
  for (int m = 1; m < 16; m <<= 1)
    #pragma unroll
    for (int rt = 0; rt < ROWTILES; rt++)
      #pragma unroll
      for (int r = 0; r < 4; r++)
        rowsum[rt][r] += __shfl_xor(rowsum[rt][r], m, 64);
  if (lr == 0) {
    // quad q holds rows rt*16 + q*4 + 0..3 of the wave's 64 rows
    float* Prow = P + ((size_t)I * NT + J) * TILE + wave * 64;
    #pragma unroll
    for (int rt = 0; rt < ROWTILES; rt++) {
      float4v v = {rowsum[rt][0], rowsum[rt][1], rowsum[rt][2], rowsum[rt][3]};
      *(float4v*)&Prow[rt * 16 + quad * 4] = v;
    }
  }

  // ---- column sums: combine 4 wave partials, coalesced store ----
  if (!diag) {
    __syncthreads();
    // tid 0..255 each own one of the 256 columns
    float s = csum_lds[0][tid] + csum_lds[1][tid] +
              csum_lds[2][tid] + csum_lds[3][tid];
    P[((size_t)J * NT + I) * TILE + tid] = s;
  }
}

// ---------------------------------------------------------------------------
// Kernel 3: per-row reduction of P + log term. 32 blocks x 256 threads,
// one thread per row r: denom[r] = sum_J P[r>>8][J][r&255] (fp32, fixed
// order), term = log(denom - e^2) - 2*pos[r mod B]; block double-reduce.
// ---------------------------------------------------------------------------
__global__ __launch_bounds__(256) void reduce_rows(
    const float* __restrict__ P, const float* __restrict__ pos,
    double* __restrict__ bpart) {
  __shared__ double sred[256];
  const int tid = threadIdx.x;
  const int r   = blockIdx.x * 256 + tid;       // 32*256 = 8192 rows
  const int I   = r >> 8;                       // 256-row tiles
  const int rr  = r & (TILE - 1);

  const float* p = P + (size_t)I * NT * TILE + rr;
  float acc = 0.0f;
  #pragma unroll 8
  for (int J = 0; J < NT; J++) acc += p[(size_t)J * TILE];

  double term = (double)(logf(acc - DIAG_E2) - 2.0f * pos[r & (BB - 1)]);
  sred[tid] = term;
  __syncthreads();
  for (int s = 128; s; s >>= 1) {
    if (tid < s) sred[tid] += sred[tid + s];
    __syncthreads();
  }
  if (tid == 0) bpart[blockIdx.x] = sred[0];
}

// ---------------------------------------------------------------------------
// Kernel 4: fold 32 block partials into the scalar loss. One wave.
// ---------------------------------------------------------------------------
__global__ __launch_bounds__(64) void final_sum(
    const double* __restrict__ bpart, float* __restrict__ out) {
  int tid = threadIdx.x;
  double v = (tid < 32) ? bpart[tid] : 0.0;
  #pragma unroll
  for (int m = 32; m; m >>= 1) v += __shfl_xor(v, m, 64);
  if (tid == 0) out[0] = (float)(v / (double)N2);
}

// ---------------------------------------------------------------------------
extern "C" void kernel_launch(void* const* d_in, const int* in_sizes, int n_in,
                              void* d_out, int out_size, void* d_ws, size_t ws_size,
                              hipStream_t stream) {
  const float* emb_i = (const float*)d_in[0];
  const float* emb_j = (const float*)d_in[1];

  // workspace layout
  __hip_bfloat16* z = (__hip_bfloat16*)d_ws;                       // 2 MiB
  float* pos   = (float*)((char*)d_ws + (size_t)N2 * DIMS * 2);    // 4096 f32
  float* P     = pos + BB;                                         // 32*32*256 f32 = 1 MiB
  double* bpart = (double*)(P + (size_t)NT * NT * TILE);           // 32 f64

  norm_kernel<<<BB / 4, 256, 0, stream>>>(emb_i, emb_j, z, pos);
  simloss_sym<<<NJOBS, 256, 0, stream>>>(z, P);
  reduce_rows<<<N2 / 256, 256, 0, stream>>>(P, pos, bpart);
  final_sum<<<1, 64, 0, stream>>>(bpart, (float*)d_out);
}

// Round 6
// 82.277 us; speedup vs baseline: 1.0381x; 1.0381x over previous
//
#include <hip/hip_runtime.h>
#include <hip/hip_bf16.h>
#include <math.h>

// Problem constants (B=4096, D=128, T=0.5 -> 1/T = 2)
#define BB       4096
#define N2       8192          // 2B rows of z
#define DIMS     128
#define NT       64            // number of 128-row tiles per matrix side
#define NJOBS    (NT * (NT + 1) / 2)   // 2080 upper-triangle tile jobs
#define TILE     128
#define LDS_PAD  8             // bf16 pad per row: breaks 256B-stride 16B-group conflicts
#define LDS_ROWW (DIMS + LDS_PAD)  // 136 shorts = 272 B

// z rows are pre-scaled by ZSCALE so the MFMA dot directly yields
// sim * 2*log2(e), i.e. exp(sim/T) = exp2(acc). ZSCALE^2 = 2.8853900818.
#define ZSCALE   1.6986436f
// diagonal term exp(2 * |z_r|^2) ~= exp(2) — subtracted in reduce.
#define DIAG_E2  7.38905609893065f

typedef __attribute__((ext_vector_type(8))) short short8;   // 8 x bf16 (4 VGPRs)
typedef __attribute__((ext_vector_type(4))) float float4v;  // MFMA C/D

// ---------------------------------------------------------------------------
// Kernel 1: normalize rows (fp32), compute positives (fp32), write z as
// bf16 scaled by ZSCALE. Also zeroes out[0] (accumulated by reduce_rows via
// float atomics; stream order + kernel boundary make the zero visible).
// One wave per row-pair r: emb_i[r] -> z[r], emb_j[r] -> z[r+B].
// ---------------------------------------------------------------------------
__global__ __launch_bounds__(256) void norm_kernel(
    const float* __restrict__ emb_i, const float* __restrict__ emb_j,
    __hip_bfloat16* __restrict__ z, float* __restrict__ pos,
    float* __restrict__ out) {
  if (blockIdx.x == 0 && threadIdx.x == 0) out[0] = 0.0f;

  int gw   = (blockIdx.x * blockDim.x + threadIdx.x) >> 6;  // row pair
  int lane = threadIdx.x & 63;
  if (gw >= BB) return;

  const float2* ei = (const float2*)(emb_i + (size_t)gw * DIMS);
  const float2* ej = (const float2*)(emb_j + (size_t)gw * DIMS);
  float2 a = ei[lane];
  float2 b = ej[lane];

  float sa = a.x * a.x + a.y * a.y;
  float sb = b.x * b.x + b.y * b.y;
  #pragma unroll
  for (int m = 32; m; m >>= 1) {
    sa += __shfl_xor(sa, m, 64);
    sb += __shfl_xor(sb, m, 64);
  }
  float inva = 1.0f / fmaxf(sqrtf(sa), 1e-12f);
  float invb = 1.0f / fmaxf(sqrtf(sb), 1e-12f);

  float zi0 = a.x * inva, zi1 = a.y * inva;
  float zj0 = b.x * invb, zj1 = b.y * invb;

  // positive pair dot in unscaled fp32 (matches reference's fp32 einsum)
  float p = zi0 * zj0 + zi1 * zj1;
  #pragma unroll
  for (int m = 32; m; m >>= 1) p += __shfl_xor(p, m, 64);
  if (lane == 0) pos[gw] = p;

  __hip_bfloat162* zr_i = (__hip_bfloat162*)(z + (size_t)gw * DIMS);
  __hip_bfloat162* zr_j = (__hip_bfloat162*)(z + (size_t)(gw + BB) * DIMS);
  __hip_bfloat162 vi, vj;
  vi.x = __float2bfloat16(zi0 * ZSCALE); vi.y = __float2bfloat16(zi1 * ZSCALE);
  vj.x = __float2bfloat16(zj0 * ZSCALE); vj.y = __float2bfloat16(zj1 * ZSCALE);
  zr_i[lane] = vi;
  zr_j[lane] = vj;
}

// ---------------------------------------------------------------------------
// Kernel 2: symmetric fused sim-GEMM + exp2 -> PRIVATE partials (no atomics).
// BYTE-IDENTICAL to the round-4 version (best measured, 83.8 total).
// Round-5 post-mortem: block count / tile size / waves-per-SIMD all have no
// effect (r0 512 blk ~ r4 2080 blk ~ r5 528 blk) and r1's direct counters
// bound sim's pipe work at ~5-8 µs -> the timed budget above the 41.5 µs
// harness fill is dominated by per-kernel fixed costs, not sim's interior.
// Block (I,J), I<J writes row-partials to P[I][J][:] and col-partials to
// P[J][I][:]; diag writes P[I][I][:]. Every cell written exactly once.
// MFMA dot is bit-identical under operand transpose, so symmetry is exact.
// ---------------------------------------------------------------------------
__global__ __launch_bounds__(256, 4) void simloss_sym(
    const __hip_bfloat16* __restrict__ z, float* __restrict__ P) {
  __shared__ short lds[TILE * LDS_ROWW];   // 128 x 136 bf16 = 34816 B
  __shared__ float csum_lds[4][TILE];      // per-wave column-sum partials

  const int tid  = threadIdx.x;
  const int wave = tid >> 6;
  const int lane = tid & 63;
  const int lr   = lane & 15;          // A-row / B-col / C-col within tile
  const int quad = lane >> 4;          // k-group for A/B, row-group for C

  // ---- decode flat job id -> (I, J) with I <= J over NT=64 ----
  // base(I) = I*(2*NT - I + 1)/2 ; float guess + integer fixup.
  const int j = blockIdx.x;
  int I = (int)((129.0f - sqrtf(16641.0f - 8.0f * (float)j)) * 0.5f);
  I = I < 0 ? 0 : (I > NT - 1 ? NT - 1 : I);
  while (I < NT - 1 && (I + 1) * (2 * NT - I) / 2 <= j) ++I;
  while (I > 0 && I * (2 * NT - I + 1) / 2 > j) --I;
  const int J = I + (j - I * (2 * NT - I + 1) / 2);
  const bool diag = (I == J);
  const int R0 = I * TILE;
  const int C0 = J * TILE;

  const ushort* zp = (const ushort*)z;

  // ---- A fragments pinned in VGPRs: rows R0 + wave*32 + rt*16 + lr ----
  short8 afrag[2][4];
  #pragma unroll
  for (int rt = 0; rt < 2; rt++) {
    const int arow = R0 + wave * 32 + rt * 16 + lr;
    const short8* ap = (const short8*)(zp + (size_t)arow * DIMS + quad * 8);
    afrag[rt][0] = ap[0];
    afrag[rt][1] = ap[4];   // +32 shorts
    afrag[rt][2] = ap[8];
    afrag[rt][3] = ap[12];
  }

  // ---- stage B tile: 128 cols x 128 dims (2048 short8, 8 per thread) ----
  {
    const short8* src = (const short8*)(zp + (size_t)C0 * DIMS);
    #pragma unroll
    for (int i = 0; i < 8; i++) {
      int idx  = tid + 256 * i;
      int row  = idx >> 4;             // 16 short8 per logical row
      int col8 = idx & 15;
      *(short8*)&lds[row * LDS_ROWW + col8 * 8] = src[idx];
    }
  }
  __syncthreads();

  float rowsum[2][4];
  #pragma unroll
  for (int rt = 0; rt < 2; rt++)
    #pragma unroll
    for (int r = 0; r < 4; r++) rowsum[rt][r] = 0.0f;

  #pragma unroll 2
  for (int t = 0; t < 8; t++) {        // 8 column tiles of 16
    const short8* bp = (const short8*)&lds[(t * 16 + lr) * LDS_ROWW + quad * 8];
    short8 b0 = bp[0];
    short8 b1 = bp[4];
    short8 b2 = bp[8];
    short8 b3 = bp[12];
    float ctile = 0.0f;
    #pragma unroll
    for (int rt = 0; rt < 2; rt++) {
      float4v acc = {0.0f, 0.0f, 0.0f, 0.0f};
      acc = __builtin_amdgcn_mfma_f32_16x16x32_bf16(afrag[rt][0], b0, acc, 0, 0, 0);
      acc = __builtin_amdgcn_mfma_f32_16x16x32_bf16(afrag[rt][1], b1, acc, 0, 0, 0);
      acc = __builtin_amdgcn_mfma_f32_16x16x32_bf16(afrag[rt][2], b2, acc, 0, 0, 0);
      acc = __builtin_amdgcn_mfma_f32_16x16x32_bf16(afrag[rt][3], b3, acc, 0, 0, 0);
      // exp(sim/T) = exp2(acc) thanks to ZSCALE pre-scaling.
      #pragma unroll
      for (int r = 0; r < 4; r++) {
        float e = __builtin_amdgcn_exp2f(acc[r]);
        rowsum[rt][r] += e;
        ctile += e;
      }
    }
    if (!diag) {  // block-uniform branch
      // column sums: reduce over the wave's 32 rows (4 regs done above, now quads)
      ctile += __shfl_xor(ctile, 16, 64);
      ctile += __shfl_xor(ctile, 32, 64);
      if (quad == 0) csum_lds[wave][t * 16 + lr] = ctile;
    }
  }

  // ---- row sums: reduce across the 16 lanes of each quad, store float4 ----
  #pragma unroll
  for (int m = 1; m < 16; m <<= 1)
    #pragma unroll
    for (int rt = 0; rt < 2; rt++)
      #pragma unroll
      for (int r = 0; r < 4; r++)
        rowsum[rt][r] += __shfl_xor(rowsum[rt][r], m, 64);
  if (lr == 0) {
    // lane (quad q) holds rows quad*4 + 0..3 of its rowtile: one float4 store
    float* Prow = P + ((size_t)I * NT + J) * TILE + wave * 32;
    #pragma unroll
    for (int rt = 0; rt < 2; rt++) {
      float4v v = {rowsum[rt][0], rowsum[rt][1], rowsum[rt][2], rowsum[rt][3]};
      *(float4v*)&Prow[rt * 16 + quad * 4] = v;
    }
  }

  // ---- column sums: combine 4 wave partials, coalesced store ----
  if (!diag) {
    __syncthreads();
    if (tid < TILE) {
      float s = csum_lds[0][tid] + csum_lds[1][tid] +
                csum_lds[2][tid] + csum_lds[3][tid];
      P[((size_t)J * NT + I) * TILE + tid] = s;
    }
  }
}

// ---------------------------------------------------------------------------
// Kernel 3: per-row reduction of P + log term + final sum (fused).
// 64 blocks x 128 threads, one thread per row r:
//   denom[r] = sum_J P[r>>7][J][r&127] (fp32, fixed order)
//   term = (log(denom - e^2) - 2*pos[r mod B]) / N2   (double)
// Block double-reduce -> ONE float atomicAdd into out[0] (zeroed by norm).
// 64 float adds of ~0.16 into ~10: error ~3e-5, far inside tolerance.
// ---------------------------------------------------------------------------
__global__ __launch_bounds__(128) void reduce_rows(
    const float* __restrict__ P, const float* __restrict__ pos,
    float* __restrict__ out) {
  __shared__ double sred[128];
  const int tid = threadIdx.x;
  const int r   = blockIdx.x * 128 + tid;       // 64*128 = 8192 rows
  const int I   = r >> 7;
  const int rr  = r & (TILE - 1);

  const float* p = P + (size_t)I * NT * TILE + rr;
  float acc = 0.0f;
  #pragma unroll 8
  for (int J = 0; J < NT; J++) acc += p[(size_t)J * TILE];

  double term = (double)(logf(acc - DIAG_E2) - 2.0f * pos[r & (BB - 1)]) /
                (double)N2;
  sred[tid] = term;
  __syncthreads();
  #pragma unroll
  for (int s = 64; s; s >>= 1) {
    if (tid < s) sred[tid] += sred[tid + s];
    __syncthreads();
  }
  if (tid == 0) atomicAdd(out, (float)sred[0]);
}

// ---------------------------------------------------------------------------
extern "C" void kernel_launch(void* const* d_in, const int* in_sizes, int n_in,
                              void* d_out, int out_size, void* d_ws, size_t ws_size,
                              hipStream_t stream) {
  const float* emb_i = (const float*)d_in[0];
  const float* emb_j = (const float*)d_in[1];

  // workspace layout
  __hip_bfloat16* z = (__hip_bfloat16*)d_ws;                       // 2 MiB
  float* pos   = (float*)((char*)d_ws + (size_t)N2 * DIMS * 2);    // 4096 f32
  float* P     = pos + BB;                                         // 64*64*128 f32 = 2 MiB

  norm_kernel<<<BB / 4, 256, 0, stream>>>(emb_i, emb_j, z, pos, (float*)d_out);
  simloss_sym<<<NJOBS, 256, 0, stream>>>(z, P);
  reduce_rows<<<N2 / 128, 128, 0, stream>>>(P, pos, (float*)d_out);
}